// Round 4
// baseline (408.737 us; speedup 1.0000x reference)
//
#include <hip/hip_runtime.h>
#include <hip/hip_bf16.h>

typedef __bf16 bf16_t;
typedef bf16_t bf16x8 __attribute__((ext_vector_type(8)));
typedef float f32x4 __attribute__((ext_vector_type(4)));
typedef unsigned short u16;
typedef unsigned int u32;

static constexpr int kHW = 192 * 320;          // 61440
static constexpr float kC = 4.77464829275686f; // 30 / (2*pi)

__device__ __forceinline__ u16 f2bf(float f) {
  u32 u = __float_as_uint(f);
  return (u16)((u + 0x7FFFu + ((u >> 16) & 1u)) >> 16);
}

__device__ __forceinline__ u32 pack2(float a, float b) {
  __hip_bfloat162 h = __float22bfloat162_rn(make_float2(a, b));
  union { __hip_bfloat162 h2; u32 u; } cv;
  cv.h2 = h;
  return cv.u;
}

// ---- d_ws layout ----
// wb  : u16 weights at byte 0 (W0..W4 pre-scaled by kC)
// bws : 1024 floats at byte 344064
// featT: u16 pre-swizzled feat tiles at byte 348160 (1920 chunks x 8 KB)
static constexpr int OFF_W0 = 0;        // [64][64] (t-col folded to bias)
static constexpr int OFF_W1 = 4096;     // [64][64]
static constexpr int OFF_W2 = 8192;     // [256][64]
static constexpr int OFF_W3 = 24576;    // [256][256]
static constexpr int OFF_W4 = 90112;    // [256][256]
static constexpr int OFF_W5 = 155648;   // [64][256] (not scaled)
static constexpr int W_TOTAL = 172032;
static constexpr int B_TOTAL = 1024;
static constexpr size_t FEAT_BYTE_OFF = 348160;
static constexpr size_t WS_NEED = FEAT_BYTE_OFF + (size_t)1920 * 8192; // 16,076,800

__global__ void convert_weights(const float* __restrict__ w0, const float* __restrict__ w1,
                                const float* __restrict__ w2, const float* __restrict__ w3,
                                const float* __restrict__ w4, const float* __restrict__ w5,
                                const float* __restrict__ b0, const float* __restrict__ b1,
                                const float* __restrict__ b2, const float* __restrict__ b3,
                                const float* __restrict__ b4, const float* __restrict__ b5,
                                u16* __restrict__ wb, float* __restrict__ bws) {
  int i = blockIdx.x * 256 + threadIdx.x;
  if (i < W_TOTAL) {
    float v, s = kC;
    if (i < OFF_W1)      { int o = i >> 6, k = i & 63; v = w0[o * 65 + k]; }
    else if (i < OFF_W2) { v = w1[i - OFF_W1]; }
    else if (i < OFF_W3) { v = w2[i - OFF_W2]; }
    else if (i < OFF_W4) { v = w3[i - OFF_W3]; }
    else if (i < OFF_W5) { v = w4[i - OFF_W4]; }
    else                 { v = w5[i - OFF_W5]; s = 1.0f; }
    wb[i] = f2bf(v * s);
  } else {
    int j = i - W_TOTAL;  // 0..1023
    float v;
    if (j < 64)       v = kC * b0[j];
    else if (j < 128) v = kC * w0[(j - 64) * 65 + 64];
    else if (j < 192) v = kC * b1[j - 128];
    else if (j < 448) v = kC * b2[j - 192];
    else if (j < 704) v = kC * b3[j - 448];
    else if (j < 960) v = kC * b4[j - 704];
    else              v = b5[j - 960];
    bws[j] = v;
  }
}

// Pre-transpose feat into the exact swizzled LDS image the main kernel wants.
// chunk = blockIdx.x (0..1919): bq = chunk/960, hw0 = (chunk%960)*64.
// image[p*64 + ((g^(p&7))*8) + e] = bf16(feat[bq][g*8+e][hw0+p])
__global__ void convert_feat(const float* __restrict__ feat, u16* __restrict__ featT) {
  const int chunk = blockIdx.x;
  const int bq  = chunk / 960;
  const int hw0 = (chunk % 960) * 64;
  const int tid = threadIdx.x;
  const int p   = tid & 63;
  const int gg  = tid >> 6;  // 0..3
  const float* fbase = feat + (size_t)bq * 64 * kHW + hw0 + p;
  u16* img = featT + (size_t)chunk * 4096;
#pragma unroll
  for (int j = 0; j < 2; ++j) {
    const int g = gg * 2 + j;
    float v[8];
#pragma unroll
    for (int e = 0; e < 8; ++e) v[e] = fbase[(size_t)(g * 8 + e) * kHW];
    uint4 pk;
    pk.x = pack2(v[0], v[1]);
    pk.y = pack2(v[2], v[3]);
    pk.z = pack2(v[4], v[5]);
    pk.w = pack2(v[6], v[7]);
    *reinterpret_cast<uint4*>(img + p * 64 + ((g ^ (p & 7)) * 8)) = pk;
  }
}

// epilogue: act = sin(2*pi*frac(acc)) = sin(30*(Wh+b)); one 8B swizzled LDS write
template<int RSO>
__device__ __forceinline__ void epilogue_sin(f32x4 acc, u16* outb, int p, int g,
                                             int quad, int sw) {
  float s0 = __builtin_amdgcn_sinf(__builtin_amdgcn_fractf(acc[0]));
  float s1 = __builtin_amdgcn_sinf(__builtin_amdgcn_fractf(acc[1]));
  float s2 = __builtin_amdgcn_sinf(__builtin_amdgcn_fractf(acc[2]));
  float s3 = __builtin_amdgcn_sinf(__builtin_amdgcn_fractf(acc[3]));
  uint2 v;
  v.x = pack2(s0, s1);
  v.y = pack2(s2, s3);
  *reinterpret_cast<uint2*>(outb + p * RSO + ((g ^ sw) * 8) + (quad & 1) * 4) = v;
}

// K=64 layer. Wave handles NOT o-tiles x all 4 p-tiles; everything unrolled.
template<int NOT, int RSI, int RSO, bool TB>
__device__ __forceinline__ void layer_small(const u16* __restrict__ wb,
                                            const float* __restrict__ bg,
                                            const float* __restrict__ bgt, float t,
                                            const u16* in, u16* outb, int wave, int lane) {
  const int l15 = lane & 15, quad = lane >> 4, sw = l15 & 7;
  bf16x8 wf[NOT][2];
  f32x4  bv[NOT];
#pragma unroll
  for (int ot = 0; ot < NOT; ++ot) {
    const int got = wave * NOT + ot;
#pragma unroll
    for (int ks = 0; ks < 2; ++ks)
      wf[ot][ks] = *reinterpret_cast<const bf16x8*>(wb + (got * 16 + l15) * 64 + ks * 32 + quad * 8);
    f32x4 b0 = *reinterpret_cast<const f32x4*>(bg + got * 16 + quad * 4);
    if constexpr (TB) {
      f32x4 b1 = *reinterpret_cast<const f32x4*>(bgt + got * 16 + quad * 4);
#pragma unroll
      for (int r = 0; r < 4; ++r) bv[ot][r] = b0[r] + t * b1[r];
    } else {
      bv[ot] = b0;
    }
  }
  bf16x8 af[4][2];
#pragma unroll
  for (int pt = 0; pt < 4; ++pt)
#pragma unroll
    for (int ks = 0; ks < 2; ++ks)
      af[pt][ks] = *reinterpret_cast<const bf16x8*>(
          in + (pt * 16 + l15) * RSI + (((ks * 4 + quad) ^ sw) * 8));
#pragma unroll
  for (int pt = 0; pt < 4; ++pt) {
    const int p = pt * 16 + l15;
#pragma unroll
    for (int ot = 0; ot < NOT; ++ot) {
      f32x4 acc = bv[ot];
      acc = __builtin_amdgcn_mfma_f32_16x16x32_bf16(wf[ot][0], af[pt][0], acc, 0, 0, 0);
      acc = __builtin_amdgcn_mfma_f32_16x16x32_bf16(wf[ot][1], af[pt][1], acc, 0, 0, 0);
      epilogue_sin<RSO>(acc, outb, p, (wave * NOT + ot) * 2 + (quad >> 1), quad, sw);
    }
  }
}

// K=256 layer. NOT o-tiles/wave; p-tiles processed in groups of PPAR with
// explicit af double-buffering (prefetch group g+1 during group g's MFMAs).
template<int NOT, int PPAR, int RSO, bool LAST>
__device__ __forceinline__ void layer_big(const u16* __restrict__ wb,
                                          const float* __restrict__ bg,
                                          const u16* in, u16* outb,
                                          float* __restrict__ outg, int wave, int lane) {
  const int l15 = lane & 15, quad = lane >> 4, sw = l15 & 7;
  bf16x8 wf[NOT][8];
#pragma unroll
  for (int ks = 0; ks < 8; ++ks)
#pragma unroll
    for (int ot = 0; ot < NOT; ++ot)
      wf[ot][ks] = *reinterpret_cast<const bf16x8*>(
          wb + ((wave * NOT + ot) * 16 + l15) * 256 + ks * 32 + quad * 8);
  f32x4 bv[NOT];
#pragma unroll
  for (int ot = 0; ot < NOT; ++ot)
    bv[ot] = *reinterpret_cast<const f32x4*>(bg + (wave * NOT + ot) * 16 + quad * 4);

  constexpr int G = 4 / PPAR;
  bf16x8 af[2][PPAR][8];
#pragma unroll
  for (int pp = 0; pp < PPAR; ++pp)
#pragma unroll
    for (int ks = 0; ks < 8; ++ks)
      af[0][pp][ks] = *reinterpret_cast<const bf16x8*>(
          in + (pp * 16 + l15) * 256 + (((ks * 4 + quad) ^ sw) * 8));

#pragma unroll
  for (int g = 0; g < G; ++g) {
    if (g + 1 < G) {
#pragma unroll
      for (int pp = 0; pp < PPAR; ++pp)
#pragma unroll
        for (int ks = 0; ks < 8; ++ks)
          af[(g + 1) & 1][pp][ks] = *reinterpret_cast<const bf16x8*>(
              in + (((g + 1) * PPAR + pp) * 16 + l15) * 256 + (((ks * 4 + quad) ^ sw) * 8));
    }
    f32x4 acc[PPAR][NOT];
#pragma unroll
    for (int pp = 0; pp < PPAR; ++pp)
#pragma unroll
      for (int ot = 0; ot < NOT; ++ot) acc[pp][ot] = bv[ot];
#pragma unroll
    for (int ks = 0; ks < 8; ++ks)
#pragma unroll
      for (int pp = 0; pp < PPAR; ++pp)
#pragma unroll
        for (int ot = 0; ot < NOT; ++ot)
          acc[pp][ot] = __builtin_amdgcn_mfma_f32_16x16x32_bf16(
              wf[ot][ks], af[g & 1][pp][ks], acc[pp][ot], 0, 0, 0);
#pragma unroll
    for (int pp = 0; pp < PPAR; ++pp) {
      const int p = (g * PPAR + pp) * 16 + l15;
#pragma unroll
      for (int ot = 0; ot < NOT; ++ot) {
        if constexpr (LAST) {
          const int o = (wave * NOT + ot) * 16 + quad * 4;
          float* dst = outg + (size_t)o * kHW + p;
#pragma unroll
          for (int r = 0; r < 4; ++r) dst[(size_t)r * kHW] = acc[pp][ot][r];
        } else {
          epilogue_sin<RSO>(acc[pp][ot], outb, p,
                            (wave * NOT + ot) * 2 + (quad >> 1), quad, sw);
        }
      }
    }
  }
}

template<bool PRE>
__global__ void __launch_bounds__(256, 2)
siren_main(const float* __restrict__ feat, const float* __restrict__ times,
           const u16* __restrict__ wb, const float* __restrict__ bws,
           const u16* __restrict__ featT, float* __restrict__ out) {
  __shared__ __align__(16) u16 A32[64 * 256];
  __shared__ __align__(16) u16 B32[64 * 256];
  u16* X = B32;         // 64x64 compact buffer (stride 64), dead once L3 writes B32
  u16* Y = B32 + 4096;  // 64x64 compact buffer

  const int tid   = threadIdx.x;
  const int bid   = blockIdx.x;
  const int c     = bid / 1920;
  const int chunk = bid % 1920;
  const int bq    = chunk / 960;
  const int hw0   = (chunk % 960) * 64;
  const float t   = times[c];
  const int wave  = tid >> 6;
  const int lane  = tid & 63;

  if constexpr (PRE) {
    const uint4* src = reinterpret_cast<const uint4*>(featT + (size_t)chunk * 4096);
    uint4* dst = reinterpret_cast<uint4*>(X);
    dst[tid]       = src[tid];
    dst[tid + 256] = src[tid + 256];
  } else {
    const int p  = tid & 63;
    const int gg = tid >> 6;
    const float* fbase = feat + (size_t)bq * 64 * kHW + hw0 + p;
#pragma unroll
    for (int j = 0; j < 2; ++j) {
      const int g = gg * 2 + j;
      float v[8];
#pragma unroll
      for (int e = 0; e < 8; ++e) v[e] = fbase[(size_t)(g * 8 + e) * kHW];
      uint4 pk;
      pk.x = pack2(v[0], v[1]);
      pk.y = pack2(v[2], v[3]);
      pk.z = pack2(v[4], v[5]);
      pk.w = pack2(v[6], v[7]);
      *reinterpret_cast<uint4*>(X + p * 64 + ((g ^ (p & 7)) * 8)) = pk;
    }
  }
  __syncthreads();

  layer_small<1, 64, 64, true >(wb + OFF_W0, bws + 0,   bws + 64, t, X, Y, wave, lane);
  __syncthreads();
  layer_small<1, 64, 64, false>(wb + OFF_W1, bws + 128, nullptr, 0.f, Y, X, wave, lane);
  __syncthreads();
  layer_small<4, 64, 256, false>(wb + OFF_W2, bws + 192, nullptr, 0.f, X, A32, wave, lane);
  __syncthreads();
  layer_big<4, 1, 256, false>(wb + OFF_W3, bws + 448, A32, B32, nullptr, wave, lane);
  __syncthreads();
  layer_big<4, 1, 256, false>(wb + OFF_W4, bws + 704, B32, A32, nullptr, wave, lane);
  __syncthreads();
  float* out_base = out + (size_t)(c * 2 + bq) * 64 * kHW + hw0;
  layer_big<1, 2, 256, true>(wb + OFF_W5, bws + 960, A32, nullptr, out_base, wave, lane);
}

extern "C" void kernel_launch(void* const* d_in, const int* in_sizes, int n_in,
                              void* d_out, int out_size, void* d_ws, size_t ws_size,
                              hipStream_t stream) {
  const float* feat  = (const float*)d_in[0];
  const float* times = (const float*)d_in[1];
  const float* w0 = (const float*)d_in[2];
  const float* b0 = (const float*)d_in[3];
  const float* w1 = (const float*)d_in[4];
  const float* b1 = (const float*)d_in[5];
  const float* w2 = (const float*)d_in[6];
  const float* b2 = (const float*)d_in[7];
  const float* w3 = (const float*)d_in[8];
  const float* b3 = (const float*)d_in[9];
  const float* w4 = (const float*)d_in[10];
  const float* b4 = (const float*)d_in[11];
  const float* w5 = (const float*)d_in[12];
  const float* b5 = (const float*)d_in[13];
  u16*   wb  = (u16*)d_ws;
  float* bws = (float*)((char*)d_ws + (size_t)W_TOTAL * 2);
  float* out = (float*)d_out;

  convert_weights<<<(W_TOTAL + B_TOTAL) / 256, 256, 0, stream>>>(
      w0, w1, w2, w3, w4, w5, b0, b1, b2, b3, b4, b5, wb, bws);

  if (ws_size >= WS_NEED) {
    u16* featT = (u16*)((char*)d_ws + FEAT_BYTE_OFF);
    convert_feat<<<1920, 256, 0, stream>>>(feat, featT);
    siren_main<true><<<5760, 256, 0, stream>>>(feat, times, wb, bws, featT, out);
  } else {
    siren_main<false><<<5760, 256, 0, stream>>>(feat, times, wb, bws, wb, out);
  }
}

// Round 5
// 392.976 us; speedup vs baseline: 1.0401x; 1.0401x over previous
//
#include <hip/hip_runtime.h>
#include <hip/hip_bf16.h>

typedef __bf16 bf16_t;
typedef bf16_t bf16x8 __attribute__((ext_vector_type(8)));
typedef float f32x4 __attribute__((ext_vector_type(4)));
typedef unsigned short u16;
typedef unsigned int u32;

static constexpr int kHW = 192 * 320;          // 61440
static constexpr float kC = 4.77464829275686f; // 30 / (2*pi)

__device__ __forceinline__ u16 f2bf(float f) {
  u32 u = __float_as_uint(f);
  return (u16)((u + 0x7FFFu + ((u >> 16) & 1u)) >> 16);
}

__device__ __forceinline__ u32 pack2(float a, float b) {
  __hip_bfloat162 h = __float22bfloat162_rn(make_float2(a, b));
  union { __hip_bfloat162 h2; u32 u; } cv;
  cv.h2 = h;
  return cv.u;
}

// Light barrier: LDS-visibility only (lgkmcnt). Leaves global loads in
// flight across the barrier -- this is what enables cross-layer weight
// prefetch; __syncthreads() would drain vmcnt(0) and kill it.
__device__ __forceinline__ void lds_barrier() {
  __asm__ volatile("s_waitcnt lgkmcnt(0)\n\ts_barrier" ::: "memory");
}

// ---- d_ws layout ----
static constexpr int OFF_W0 = 0;        // [64][64] (t-col folded to bias)
static constexpr int OFF_W1 = 4096;     // [64][64]
static constexpr int OFF_W2 = 8192;     // [256][64]
static constexpr int OFF_W3 = 24576;    // [256][256]
static constexpr int OFF_W4 = 90112;    // [256][256]
static constexpr int OFF_W5 = 155648;   // [64][256] (not scaled)
static constexpr int W_TOTAL = 172032;
static constexpr int B_TOTAL = 1024;
static constexpr size_t FEAT_BYTE_OFF = 348160;
static constexpr size_t WS_NEED = FEAT_BYTE_OFF + (size_t)1920 * 8192;

__global__ void convert_weights(const float* __restrict__ w0, const float* __restrict__ w1,
                                const float* __restrict__ w2, const float* __restrict__ w3,
                                const float* __restrict__ w4, const float* __restrict__ w5,
                                const float* __restrict__ b0, const float* __restrict__ b1,
                                const float* __restrict__ b2, const float* __restrict__ b3,
                                const float* __restrict__ b4, const float* __restrict__ b5,
                                u16* __restrict__ wb, float* __restrict__ bws) {
  int i = blockIdx.x * 256 + threadIdx.x;
  if (i < W_TOTAL) {
    float v, s = kC;
    if (i < OFF_W1)      { int o = i >> 6, k = i & 63; v = w0[o * 65 + k]; }
    else if (i < OFF_W2) { v = w1[i - OFF_W1]; }
    else if (i < OFF_W3) { v = w2[i - OFF_W2]; }
    else if (i < OFF_W4) { v = w3[i - OFF_W3]; }
    else if (i < OFF_W5) { v = w4[i - OFF_W4]; }
    else                 { v = w5[i - OFF_W5]; s = 1.0f; }
    wb[i] = f2bf(v * s);
  } else {
    int j = i - W_TOTAL;
    float v;
    if (j < 64)       v = kC * b0[j];
    else if (j < 128) v = kC * w0[(j - 64) * 65 + 64];
    else if (j < 192) v = kC * b1[j - 128];
    else if (j < 448) v = kC * b2[j - 192];
    else if (j < 704) v = kC * b3[j - 448];
    else if (j < 960) v = kC * b4[j - 704];
    else              v = b5[j - 960];
    bws[j] = v;
  }
}

// Pre-transpose feat into the swizzled bf16 LDS image the main kernel wants.
__global__ void convert_feat(const float* __restrict__ feat, u16* __restrict__ featT) {
  const int chunk = blockIdx.x;
  const int bq  = chunk / 960;
  const int hw0 = (chunk % 960) * 64;
  const int tid = threadIdx.x;
  const int p   = tid & 63;
  const int gg  = tid >> 6;
  const float* fbase = feat + (size_t)bq * 64 * kHW + hw0 + p;
  u16* img = featT + (size_t)chunk * 4096;
#pragma unroll
  for (int j = 0; j < 2; ++j) {
    const int g = gg * 2 + j;
    float v[8];
#pragma unroll
    for (int e = 0; e < 8; ++e) v[e] = fbase[(size_t)(g * 8 + e) * kHW];
    uint4 pk;
    pk.x = pack2(v[0], v[1]);
    pk.y = pack2(v[2], v[3]);
    pk.z = pack2(v[4], v[5]);
    pk.w = pack2(v[6], v[7]);
    *reinterpret_cast<uint4*>(img + p * 64 + ((g ^ (p & 7)) * 8)) = pk;
  }
}

template<int RSO>
__device__ __forceinline__ void epilogue_sin(f32x4 acc, u16* outb, int p, int g,
                                             int quad, int sw) {
  float s0 = __builtin_amdgcn_sinf(__builtin_amdgcn_fractf(acc[0]));
  float s1 = __builtin_amdgcn_sinf(__builtin_amdgcn_fractf(acc[1]));
  float s2 = __builtin_amdgcn_sinf(__builtin_amdgcn_fractf(acc[2]));
  float s3 = __builtin_amdgcn_sinf(__builtin_amdgcn_fractf(acc[3]));
  uint2 v;
  v.x = pack2(s0, s1);
  v.y = pack2(s2, s3);
  *reinterpret_cast<uint2*>(outb + p * RSO + ((g ^ sw) * 8) + (quad & 1) * 4) = v;
}

template<int NOT, int KT, int K>
__device__ __forceinline__ void load_wf(bf16x8 (&wf)[NOT][KT], const u16* __restrict__ wb,
                                        int wave, int l15, int quad) {
#pragma unroll
  for (int ks = 0; ks < KT; ++ks)
#pragma unroll
    for (int ot = 0; ot < NOT; ++ot)
      wf[ot][ks] = *reinterpret_cast<const bf16x8*>(
          wb + ((wave * NOT + ot) * 16 + l15) * K + ks * 32 + quad * 8);
}

template<int NOT>
__device__ __forceinline__ void load_bv(f32x4 (&bv)[NOT], const float* __restrict__ bg,
                                        int wave, int quad) {
#pragma unroll
  for (int ot = 0; ot < NOT; ++ot)
    bv[ot] = *reinterpret_cast<const f32x4*>(bg + (wave * NOT + ot) * 16 + quad * 4);
}

template<bool PRE>
__global__ void __launch_bounds__(256, 2)
siren_main(const float* __restrict__ feat, const float* __restrict__ times,
           const u16* __restrict__ wb, const float* __restrict__ bws,
           const u16* __restrict__ featT, float* __restrict__ out) {
  __shared__ __align__(16) u16 A32[64 * 256];
  __shared__ __align__(16) u16 B32[64 * 256];
  u16* X = B32;         // 64x64 compact (stride 64); dead before L3 writes B32
  u16* Y = B32 + 4096;

  const int tid   = threadIdx.x;
  const int bid   = blockIdx.x;
  const int c     = bid / 1920;
  const int chunk = bid % 1920;
  const int bq    = chunk / 960;
  const int hw0   = (chunk % 960) * 64;
  const float t   = times[c];
  const int wave  = tid >> 6;
  const int lane  = tid & 63;
  const int l15   = lane & 15;
  const int quad  = lane >> 4;
  const int sw    = l15 & 7;

  // ---- preload L0 + prefetch L1 weights (covered by feat staging) ----
  bf16x8 wf0[1][2], wf1[1][2];
  load_wf<1, 2, 64>(wf0, wb + OFF_W0, wave, l15, quad);
  load_wf<1, 2, 64>(wf1, wb + OFF_W1, wave, l15, quad);
  f32x4 bv0;
  {
    f32x4 cb = *reinterpret_cast<const f32x4*>(bws + wave * 16 + quad * 4);
    f32x4 cw = *reinterpret_cast<const f32x4*>(bws + 64 + wave * 16 + quad * 4);
#pragma unroll
    for (int r = 0; r < 4; ++r) bv0[r] = cb[r] + t * cw[r];
  }
  f32x4 bv1 = *reinterpret_cast<const f32x4*>(bws + 128 + wave * 16 + quad * 4);

  // ---- stage input into X ----
  if constexpr (PRE) {
    const uint4* src = reinterpret_cast<const uint4*>(featT + (size_t)chunk * 4096);
    uint4* dst = reinterpret_cast<uint4*>(X);
    dst[tid]       = src[tid];
    dst[tid + 256] = src[tid + 256];
  } else {
    const int p  = tid & 63;
    const int gg = tid >> 6;
    const float* fbase = feat + (size_t)bq * 64 * kHW + hw0 + p;
#pragma unroll
    for (int j = 0; j < 2; ++j) {
      const int g = gg * 2 + j;
      float v[8];
#pragma unroll
      for (int e = 0; e < 8; ++e) v[e] = fbase[(size_t)(g * 8 + e) * kHW];
      uint4 pk;
      pk.x = pack2(v[0], v[1]);
      pk.y = pack2(v[2], v[3]);
      pk.z = pack2(v[4], v[5]);
      pk.w = pack2(v[6], v[7]);
      *reinterpret_cast<uint4*>(X + p * 64 + ((g ^ (p & 7)) * 8)) = pk;
    }
  }
  lds_barrier();

  bf16x8 wf2[4][2];
  f32x4  bv2[4];
  // ---- L0: X -> Y (K=64, N=64, NOT=1) ----
  {
    bf16x8 af[4][2];
#pragma unroll
    for (int pt = 0; pt < 4; ++pt)
#pragma unroll
      for (int ks = 0; ks < 2; ++ks)
        af[pt][ks] = *reinterpret_cast<const bf16x8*>(
            X + (pt * 16 + l15) * 64 + (((ks * 4 + quad) ^ sw) * 8));
    f32x4 acc[4];
#pragma unroll
    for (int pt = 0; pt < 4; ++pt) {
      acc[pt] = bv0;
      acc[pt] = __builtin_amdgcn_mfma_f32_16x16x32_bf16(wf0[0][0], af[pt][0], acc[pt], 0, 0, 0);
      acc[pt] = __builtin_amdgcn_mfma_f32_16x16x32_bf16(wf0[0][1], af[pt][1], acc[pt], 0, 0, 0);
    }
    // prefetch L2 weights (fly during epilogue + barrier + L1)
    load_wf<4, 2, 64>(wf2, wb + OFF_W2, wave, l15, quad);
    load_bv<4>(bv2, bws + 192, wave, quad);
#pragma unroll
    for (int pt = 0; pt < 4; ++pt)
      epilogue_sin<64>(acc[pt], Y, pt * 16 + l15, wave * 2 + (quad >> 1), quad, sw);
  }
  lds_barrier();

  // ---- L1: Y -> X (K=64, N=64, NOT=1) ----
  {
    bf16x8 af[4][2];
#pragma unroll
    for (int pt = 0; pt < 4; ++pt)
#pragma unroll
      for (int ks = 0; ks < 2; ++ks)
        af[pt][ks] = *reinterpret_cast<const bf16x8*>(
            Y + (pt * 16 + l15) * 64 + (((ks * 4 + quad) ^ sw) * 8));
    f32x4 acc[4];
#pragma unroll
    for (int pt = 0; pt < 4; ++pt) {
      acc[pt] = bv1;
      acc[pt] = __builtin_amdgcn_mfma_f32_16x16x32_bf16(wf1[0][0], af[pt][0], acc[pt], 0, 0, 0);
      acc[pt] = __builtin_amdgcn_mfma_f32_16x16x32_bf16(wf1[0][1], af[pt][1], acc[pt], 0, 0, 0);
    }
#pragma unroll
    for (int pt = 0; pt < 4; ++pt)
      epilogue_sin<64>(acc[pt], X, pt * 16 + l15, wave * 2 + (quad >> 1), quad, sw);
  }
  lds_barrier();

  bf16x8 wf3[4][8];
  f32x4  bv3[4];
  // ---- L2: X -> A32 (K=64, N=256, NOT=4) ----
  {
    bf16x8 af[4][2];
#pragma unroll
    for (int pt = 0; pt < 4; ++pt)
#pragma unroll
      for (int ks = 0; ks < 2; ++ks)
        af[pt][ks] = *reinterpret_cast<const bf16x8*>(
            X + (pt * 16 + l15) * 64 + (((ks * 4 + quad) ^ sw) * 8));
    f32x4 acc[4][4];
#pragma unroll
    for (int pt = 0; pt < 4; ++pt)
#pragma unroll
      for (int ot = 0; ot < 4; ++ot) {
        acc[pt][ot] = bv2[ot];
        acc[pt][ot] = __builtin_amdgcn_mfma_f32_16x16x32_bf16(wf2[ot][0], af[pt][0], acc[pt][ot], 0, 0, 0);
        acc[pt][ot] = __builtin_amdgcn_mfma_f32_16x16x32_bf16(wf2[ot][1], af[pt][1], acc[pt][ot], 0, 0, 0);
      }
    // prefetch L3 weights (wf2 now dead; fly during 16-tile epilogue + barrier)
    load_wf<4, 8, 256>(wf3, wb + OFF_W3, wave, l15, quad);
    load_bv<4>(bv3, bws + 448, wave, quad);
#pragma unroll
    for (int pt = 0; pt < 4; ++pt)
#pragma unroll
      for (int ot = 0; ot < 4; ++ot)
        epilogue_sin<256>(acc[pt][ot], A32, pt * 16 + l15,
                          (wave * 4 + ot) * 2 + (quad >> 1), quad, sw);
  }
  lds_barrier();

  bf16x8 wf4[4][8];
  f32x4  bv4[4];
  // ---- L3: A32 -> B32 (K=256, N=256, NOT=4) ----
  {
#pragma unroll
    for (int pt = 0; pt < 4; ++pt) {
      bf16x8 af[8];
#pragma unroll
      for (int ks = 0; ks < 8; ++ks)
        af[ks] = *reinterpret_cast<const bf16x8*>(
            A32 + (pt * 16 + l15) * 256 + (((ks * 4 + quad) ^ sw) * 8));
      f32x4 acc[4];
#pragma unroll
      for (int ot = 0; ot < 4; ++ot) acc[ot] = bv3[ot];
#pragma unroll
      for (int ks = 0; ks < 8; ++ks)
#pragma unroll
        for (int ot = 0; ot < 4; ++ot)
          acc[ot] = __builtin_amdgcn_mfma_f32_16x16x32_bf16(wf3[ot][ks], af[ks], acc[ot], 0, 0, 0);
      if (pt == 3) {  // wf3 dead: prefetch L4 weights
        load_wf<4, 8, 256>(wf4, wb + OFF_W4, wave, l15, quad);
        load_bv<4>(bv4, bws + 704, wave, quad);
      }
#pragma unroll
      for (int ot = 0; ot < 4; ++ot)
        epilogue_sin<256>(acc[ot], B32, pt * 16 + l15,
                          (wave * 4 + ot) * 2 + (quad >> 1), quad, sw);
    }
  }
  lds_barrier();

  bf16x8 wf5[1][8];
  f32x4  bv5;
  // ---- L4: B32 -> A32 (K=256, N=256, NOT=4) ----
  {
#pragma unroll
    for (int pt = 0; pt < 4; ++pt) {
      bf16x8 af[8];
#pragma unroll
      for (int ks = 0; ks < 8; ++ks)
        af[ks] = *reinterpret_cast<const bf16x8*>(
            B32 + (pt * 16 + l15) * 256 + (((ks * 4 + quad) ^ sw) * 8));
      f32x4 acc[4];
#pragma unroll
      for (int ot = 0; ot < 4; ++ot) acc[ot] = bv4[ot];
#pragma unroll
      for (int ks = 0; ks < 8; ++ks)
#pragma unroll
        for (int ot = 0; ot < 4; ++ot)
          acc[ot] = __builtin_amdgcn_mfma_f32_16x16x32_bf16(wf4[ot][ks], af[ks], acc[ot], 0, 0, 0);
      if (pt == 3) {  // wf4 dead: prefetch L5 weights
        load_wf<1, 8, 256>(wf5, wb + OFF_W5, wave, l15, quad);
        bv5 = *reinterpret_cast<const f32x4*>(bws + 960 + wave * 16 + quad * 4);
      }
#pragma unroll
      for (int ot = 0; ot < 4; ++ot)
        epilogue_sin<256>(acc[ot], A32, pt * 16 + l15,
                          (wave * 4 + ot) * 2 + (quad >> 1), quad, sw);
    }
  }
  lds_barrier();

  // ---- L5: A32 -> global (K=256, N=64, NOT=1) ----
  {
    float* out_base = out + (size_t)(c * 2 + bq) * 64 * kHW + hw0;
#pragma unroll
    for (int pt = 0; pt < 4; ++pt) {
      bf16x8 af[8];
#pragma unroll
      for (int ks = 0; ks < 8; ++ks)
        af[ks] = *reinterpret_cast<const bf16x8*>(
            A32 + (pt * 16 + l15) * 256 + (((ks * 4 + quad) ^ sw) * 8));
      f32x4 acc = bv5;
#pragma unroll
      for (int ks = 0; ks < 8; ++ks)
        acc = __builtin_amdgcn_mfma_f32_16x16x32_bf16(wf5[0][ks], af[ks], acc, 0, 0, 0);
      const int p = pt * 16 + l15;
      const int o = wave * 16 + quad * 4;
      float* dst = out_base + (size_t)o * kHW + p;
#pragma unroll
      for (int r = 0; r < 4; ++r) dst[(size_t)r * kHW] = acc[r];
    }
  }
}

extern "C" void kernel_launch(void* const* d_in, const int* in_sizes, int n_in,
                              void* d_out, int out_size, void* d_ws, size_t ws_size,
                              hipStream_t stream) {
  const float* feat  = (const float*)d_in[0];
  const float* times = (const float*)d_in[1];
  const float* w0 = (const float*)d_in[2];
  const float* b0 = (const float*)d_in[3];
  const float* w1 = (const float*)d_in[4];
  const float* b1 = (const float*)d_in[5];
  const float* w2 = (const float*)d_in[6];
  const float* b2 = (const float*)d_in[7];
  const float* w3 = (const float*)d_in[8];
  const float* b3 = (const float*)d_in[9];
  const float* w4 = (const float*)d_in[10];
  const float* b4 = (const float*)d_in[11];
  const float* w5 = (const float*)d_in[12];
  const float* b5 = (const float*)d_in[13];
  u16*   wb  = (u16*)d_ws;
  float* bws = (float*)((char*)d_ws + (size_t)W_TOTAL * 2);
  float* out = (float*)d_out;

  convert_weights<<<(W_TOTAL + B_TOTAL) / 256, 256, 0, stream>>>(
      w0, w1, w2, w3, w4, w5, b0, b1, b2, b3, b4, b5, wb, bws);

  if (ws_size >= WS_NEED) {
    u16* featT = (u16*)((char*)d_ws + FEAT_BYTE_OFF);
    convert_feat<<<1920, 256, 0, stream>>>(feat, featT);
    siren_main<true><<<5760, 256, 0, stream>>>(feat, times, wb, bws, featT, out);
  } else {
    siren_main<false><<<5760, 256, 0, stream>>>(feat, times, wb, bws, wb, out);
  }
}

// Round 6
// 390.536 us; speedup vs baseline: 1.0466x; 1.0062x over previous
//
#include <hip/hip_runtime.h>
#include <hip/hip_bf16.h>

typedef __bf16 bf16_t;
typedef bf16_t bf16x8 __attribute__((ext_vector_type(8)));
typedef float f32x4 __attribute__((ext_vector_type(4)));
typedef unsigned short u16;
typedef unsigned int u32;

static constexpr int kHW = 192 * 320;          // 61440
static constexpr float kC = 4.77464829275686f; // 30 / (2*pi)

__device__ __forceinline__ u16 f2bf(float f) {
  u32 u = __float_as_uint(f);
  return (u16)((u + 0x7FFFu + ((u >> 16) & 1u)) >> 16);
}

__device__ __forceinline__ u32 pack2(float a, float b) {
  __hip_bfloat162 h = __float22bfloat162_rn(make_float2(a, b));
  union { __hip_bfloat162 h2; u32 u; } cv;
  cv.h2 = h;
  return cv.u;
}

// LDS-visibility-only barrier: leaves global loads (weight prefetch) in flight.
__device__ __forceinline__ void lds_barrier() {
  __asm__ volatile("s_waitcnt lgkmcnt(0)\n\ts_barrier" ::: "memory");
}

// ---- d_ws layout ----
static constexpr int OFF_W0 = 0;        // [64][64] (t-col folded to bias)
static constexpr int OFF_W1 = 4096;     // [64][64]
static constexpr int OFF_W2 = 8192;     // [256][64]
static constexpr int OFF_W3 = 24576;    // [256][256]
static constexpr int OFF_W4 = 90112;    // [256][256]
static constexpr int OFF_W5 = 155648;   // [64][256] (not scaled)
static constexpr int W_TOTAL = 172032;
static constexpr int B_TOTAL = 1024;
static constexpr size_t FEAT_BYTE_OFF = 348160;
static constexpr size_t WS_NEED = FEAT_BYTE_OFF + (size_t)1920 * 8192;

__global__ void convert_weights(const float* __restrict__ w0, const float* __restrict__ w1,
                                const float* __restrict__ w2, const float* __restrict__ w3,
                                const float* __restrict__ w4, const float* __restrict__ w5,
                                const float* __restrict__ b0, const float* __restrict__ b1,
                                const float* __restrict__ b2, const float* __restrict__ b3,
                                const float* __restrict__ b4, const float* __restrict__ b5,
                                u16* __restrict__ wb, float* __restrict__ bws) {
  int i = blockIdx.x * 256 + threadIdx.x;
  if (i < W_TOTAL) {
    float v, s = kC;
    if (i < OFF_W1)      { int o = i >> 6, k = i & 63; v = w0[o * 65 + k]; }
    else if (i < OFF_W2) { v = w1[i - OFF_W1]; }
    else if (i < OFF_W3) { v = w2[i - OFF_W2]; }
    else if (i < OFF_W4) { v = w3[i - OFF_W3]; }
    else if (i < OFF_W5) { v = w4[i - OFF_W4]; }
    else                 { v = w5[i - OFF_W5]; s = 1.0f; }
    wb[i] = f2bf(v * s);
  } else {
    int j = i - W_TOTAL;
    float v;
    if (j < 64)       v = kC * b0[j];
    else if (j < 128) v = kC * w0[(j - 64) * 65 + 64];
    else if (j < 192) v = kC * b1[j - 128];
    else if (j < 448) v = kC * b2[j - 192];
    else if (j < 704) v = kC * b3[j - 448];
    else if (j < 960) v = kC * b4[j - 704];
    else              v = b5[j - 960];
    bws[j] = v;
  }
}

// Pre-transpose feat into the swizzled bf16 image (the exact L0 A-frag layout).
__global__ void convert_feat(const float* __restrict__ feat, u16* __restrict__ featT) {
  const int chunk = blockIdx.x;
  const int bq  = chunk / 960;
  const int hw0 = (chunk % 960) * 64;
  const int tid = threadIdx.x;
  const int p   = tid & 63;
  const int gg  = tid >> 6;
  const float* fbase = feat + (size_t)bq * 64 * kHW + hw0 + p;
  u16* img = featT + (size_t)chunk * 4096;
#pragma unroll
  for (int j = 0; j < 2; ++j) {
    const int g = gg * 2 + j;
    float v[8];
#pragma unroll
    for (int e = 0; e < 8; ++e) v[e] = fbase[(size_t)(g * 8 + e) * kHW];
    uint4 pk;
    pk.x = pack2(v[0], v[1]);
    pk.y = pack2(v[2], v[3]);
    pk.z = pack2(v[4], v[5]);
    pk.w = pack2(v[6], v[7]);
    *reinterpret_cast<uint4*>(img + p * 64 + ((g ^ (p & 7)) * 8)) = pk;
  }
}

template<int RSO>
__device__ __forceinline__ void epilogue_sin(f32x4 acc, u16* outb, int p, int g,
                                             int quad, int sw) {
  float s0 = __builtin_amdgcn_sinf(__builtin_amdgcn_fractf(acc[0]));
  float s1 = __builtin_amdgcn_sinf(__builtin_amdgcn_fractf(acc[1]));
  float s2 = __builtin_amdgcn_sinf(__builtin_amdgcn_fractf(acc[2]));
  float s3 = __builtin_amdgcn_sinf(__builtin_amdgcn_fractf(acc[3]));
  uint2 v;
  v.x = pack2(s0, s1);
  v.y = pack2(s2, s3);
  *reinterpret_cast<uint2*>(outb + p * RSO + ((g ^ sw) * 8) + (quad & 1) * 4) = v;
}

__device__ __forceinline__ f32x4 mf(bf16x8 a, bf16x8 b, f32x4 c) {
  return __builtin_amdgcn_mfma_f32_16x16x32_bf16(a, b, c, 0, 0, 0);
}

template<bool PRE>
__global__ __attribute__((amdgpu_waves_per_eu(2, 2)))
void __launch_bounds__(256)
siren_main(const float* __restrict__ feat, const float* __restrict__ times,
           const u16* __restrict__ wb, const float* __restrict__ bws,
           const u16* __restrict__ featT, float* __restrict__ out) {
  __shared__ __align__(16) u16 A32[64 * 256];   // 32 KB
  __shared__ __align__(16) u16 B32[64 * 256];   // 32 KB
  u16* X = B32;         // 64x64 compact (stride 64), aliases B32 (dead by L3)
  u16* Y = B32 + 4096;

  const int tid   = threadIdx.x;
  const int bid   = blockIdx.x;
  const int c     = bid / 1920;
  const int chunk = bid % 1920;
  const int bq    = chunk / 960;
  const int hw0   = (chunk % 960) * 64;
  const float t   = times[c];
  const int wave  = tid >> 6;
  const int lane  = tid & 63;
  const int l15   = lane & 15;
  const int quad  = lane >> 4;
  const int sw    = l15 & 7;

  // ---------- helpers ----------
  auto read_af8 = [&](bf16x8 (&af)[8], const u16* in, int pt) {
#pragma unroll
    for (int ks = 0; ks < 8; ++ks)
      af[ks] = *reinterpret_cast<const bf16x8*>(
          in + (pt * 16 + l15) * 256 + (((ks * 4 + quad) ^ sw) * 8));
  };
  auto read_af2 = [&](bf16x8 (&af)[2], const u16* in, int pt) {
#pragma unroll
    for (int ks = 0; ks < 2; ++ks)
      af[ks] = *reinterpret_cast<const bf16x8*>(
          in + (pt * 16 + l15) * 64 + (((ks * 4 + quad) ^ sw) * 8));
  };
  auto load_wf_half = [&](bf16x8 (&wf)[4][4], const u16* wbase, int kh) {
#pragma unroll
    for (int ks = 0; ks < 4; ++ks)
#pragma unroll
      for (int ot = 0; ot < 4; ++ot)
        wf[ot][ks] = *reinterpret_cast<const bf16x8*>(
            wbase + ((wave * 4 + ot) * 16 + l15) * 256 + (kh * 4 + ks) * 32 + quad * 8);
  };
  auto load_bv4 = [&](f32x4 (&bv)[4], const float* bg) {
#pragma unroll
    for (int ot = 0; ot < 4; ++ot)
      bv[ot] = *reinterpret_cast<const f32x4*>(bg + (wave * 4 + ot) * 16 + quad * 4);
  };
  auto mfma_pt = [&](f32x4 (&acc)[4], bf16x8 (&wa)[4][4], bf16x8 (&wbh)[4][4],
                     bf16x8 (&af)[8], const f32x4 (&bv)[4]) {
#pragma unroll
    for (int ot = 0; ot < 4; ++ot) acc[ot] = bv[ot];
#pragma unroll
    for (int ks = 0; ks < 8; ++ks)
#pragma unroll
      for (int ot = 0; ot < 4; ++ot)
        acc[ot] = mf(ks < 4 ? wa[ot][ks] : wbh[ot][ks - 4], af[ks], acc[ot]);
  };
  auto epi_pt4 = [&](f32x4 (&acc)[4], u16* outb, int pt) {
#pragma unroll
    for (int ot = 0; ot < 4; ++ot)
      epilogue_sin<256>(acc[ot], outb, pt * 16 + l15,
                        (wave * 4 + ot) * 2 + (quad >> 1), quad, sw);
  };

  // ---------- preload L0/L1 weights + biases ----------
  bf16x8 wf0[2], wf1[2];
#pragma unroll
  for (int ks = 0; ks < 2; ++ks) {
    wf0[ks] = *reinterpret_cast<const bf16x8*>(wb + OFF_W0 + (wave * 16 + l15) * 64 + ks * 32 + quad * 8);
    wf1[ks] = *reinterpret_cast<const bf16x8*>(wb + OFF_W1 + (wave * 16 + l15) * 64 + ks * 32 + quad * 8);
  }
  f32x4 bv0, bv1;
  {
    f32x4 cb = *reinterpret_cast<const f32x4*>(bws + wave * 16 + quad * 4);
    f32x4 cw = *reinterpret_cast<const f32x4*>(bws + 64 + wave * 16 + quad * 4);
#pragma unroll
    for (int r = 0; r < 4; ++r) bv0[r] = cb[r] + t * cw[r];
    bv1 = *reinterpret_cast<const f32x4*>(bws + 128 + wave * 16 + quad * 4);
  }

  bf16x8 wf2[4][2];
  f32x4  bv2[4];

  // ---------- L0: featT(global) or X(LDS) -> Y ----------
  if constexpr (PRE) {
    const u16* fsrc = featT + (size_t)chunk * 4096;
    bf16x8 a0[2], a1[2];
    auto rdg = [&](bf16x8 (&a)[2], int pt) {
#pragma unroll
      for (int ks = 0; ks < 2; ++ks)
        a[ks] = *reinterpret_cast<const bf16x8*>(
            fsrc + (pt * 16 + l15) * 64 + (((ks * 4 + quad) ^ sw) * 8));
    };
    rdg(a0, 0);
    rdg(a1, 1);
    // L2-layer weights: issue now, consumed two layers later
#pragma unroll
    for (int ks = 0; ks < 2; ++ks)
#pragma unroll
      for (int ot = 0; ot < 4; ++ot)
        wf2[ot][ks] = *reinterpret_cast<const bf16x8*>(
            wb + OFF_W2 + ((wave * 4 + ot) * 16 + l15) * 64 + ks * 32 + quad * 8);
    load_bv4(bv2, bws + 192);

    f32x4 acc;
    acc = bv0; acc = mf(wf0[0], a0[0], acc); acc = mf(wf0[1], a0[1], acc);
    rdg(a0, 2);
    epilogue_sin<64>(acc, Y, 0 * 16 + l15, wave * 2 + (quad >> 1), quad, sw);
    acc = bv0; acc = mf(wf0[0], a1[0], acc); acc = mf(wf0[1], a1[1], acc);
    rdg(a1, 3);
    epilogue_sin<64>(acc, Y, 1 * 16 + l15, wave * 2 + (quad >> 1), quad, sw);
    acc = bv0; acc = mf(wf0[0], a0[0], acc); acc = mf(wf0[1], a0[1], acc);
    epilogue_sin<64>(acc, Y, 2 * 16 + l15, wave * 2 + (quad >> 1), quad, sw);
    acc = bv0; acc = mf(wf0[0], a1[0], acc); acc = mf(wf0[1], a1[1], acc);
    epilogue_sin<64>(acc, Y, 3 * 16 + l15, wave * 2 + (quad >> 1), quad, sw);
  } else {
    // fallback: stage into X, then classic LDS path
    {
      const int p  = tid & 63;
      const int gg = tid >> 6;
      const float* fbase = feat + (size_t)bq * 64 * kHW + hw0 + p;
#pragma unroll
      for (int j = 0; j < 2; ++j) {
        const int g = gg * 2 + j;
        float v[8];
#pragma unroll
        for (int e = 0; e < 8; ++e) v[e] = fbase[(size_t)(g * 8 + e) * kHW];
        uint4 pk;
        pk.x = pack2(v[0], v[1]);
        pk.y = pack2(v[2], v[3]);
        pk.z = pack2(v[4], v[5]);
        pk.w = pack2(v[6], v[7]);
        *reinterpret_cast<uint4*>(X + p * 64 + ((g ^ (p & 7)) * 8)) = pk;
      }
    }
    lds_barrier();
#pragma unroll
    for (int ks = 0; ks < 2; ++ks)
#pragma unroll
      for (int ot = 0; ot < 4; ++ot)
        wf2[ot][ks] = *reinterpret_cast<const bf16x8*>(
            wb + OFF_W2 + ((wave * 4 + ot) * 16 + l15) * 64 + ks * 32 + quad * 8);
    load_bv4(bv2, bws + 192);
#pragma unroll
    for (int pt = 0; pt < 4; ++pt) {
      bf16x8 a[2];
      read_af2(a, X, pt);
      f32x4 acc = bv0;
      acc = mf(wf0[0], a[0], acc); acc = mf(wf0[1], a[1], acc);
      epilogue_sin<64>(acc, Y, pt * 16 + l15, wave * 2 + (quad >> 1), quad, sw);
    }
  }
  lds_barrier();

  // ---------- L1: Y -> X ; prefetch first half of L3 weights ----------
  bf16x8 wf3a[4][4], wf3b[4][4];
  f32x4  bv3[4];
  {
    bf16x8 a0[2], a1[2];
    read_af2(a0, Y, 0);
    read_af2(a1, Y, 1);
    load_wf_half(wf3a, wb + OFF_W3, 0);   // flies during L1+epi+barrier+L2
    load_bv4(bv3, bws + 448);
    f32x4 acc;
    acc = bv1; acc = mf(wf1[0], a0[0], acc); acc = mf(wf1[1], a0[1], acc);
    read_af2(a0, Y, 2);
    epilogue_sin<64>(acc, X, 0 * 16 + l15, wave * 2 + (quad >> 1), quad, sw);
    acc = bv1; acc = mf(wf1[0], a1[0], acc); acc = mf(wf1[1], a1[1], acc);
    read_af2(a1, Y, 3);
    epilogue_sin<64>(acc, X, 1 * 16 + l15, wave * 2 + (quad >> 1), quad, sw);
    acc = bv1; acc = mf(wf1[0], a0[0], acc); acc = mf(wf1[1], a0[1], acc);
    epilogue_sin<64>(acc, X, 2 * 16 + l15, wave * 2 + (quad >> 1), quad, sw);
    acc = bv1; acc = mf(wf1[0], a1[0], acc); acc = mf(wf1[1], a1[1], acc);
    epilogue_sin<64>(acc, X, 3 * 16 + l15, wave * 2 + (quad >> 1), quad, sw);
  }
  lds_barrier();

  // ---------- L2: X -> A32 (N=256, NOT=4) ; prefetch second half of L3 ----------
  {
    bf16x8 a0[2], a1[2];
    read_af2(a0, X, 0);
    read_af2(a1, X, 1);
    {
      f32x4 acc[4];
#pragma unroll
      for (int ot = 0; ot < 4; ++ot) {
        acc[ot] = bv2[ot];
        acc[ot] = mf(wf2[ot][0], a0[0], acc[ot]);
        acc[ot] = mf(wf2[ot][1], a0[1], acc[ot]);
      }
      read_af2(a0, X, 2);
      epi_pt4(acc, A32, 0);
    }
    {
      f32x4 acc[4];
#pragma unroll
      for (int ot = 0; ot < 4; ++ot) {
        acc[ot] = bv2[ot];
        acc[ot] = mf(wf2[ot][0], a1[0], acc[ot]);
        acc[ot] = mf(wf2[ot][1], a1[1], acc[ot]);
      }
      read_af2(a1, X, 3);
      epi_pt4(acc, A32, 1);
    }
    {
      f32x4 acc[4];
#pragma unroll
      for (int ot = 0; ot < 4; ++ot) {
        acc[ot] = bv2[ot];
        acc[ot] = mf(wf2[ot][0], a0[0], acc[ot]);
        acc[ot] = mf(wf2[ot][1], a0[1], acc[ot]);
      }
      load_wf_half(wf3b, wb + OFF_W3, 1);   // wf2 nearly dead; 64 regs free
      epi_pt4(acc, A32, 2);
    }
    {
      f32x4 acc[4];
#pragma unroll
      for (int ot = 0; ot < 4; ++ot) {
        acc[ot] = bv2[ot];
        acc[ot] = mf(wf2[ot][0], a1[0], acc[ot]);
        acc[ot] = mf(wf2[ot][1], a1[1], acc[ot]);
      }
      epi_pt4(acc, A32, 3);
    }
  }
  lds_barrier();

  // ---------- L3: A32 -> B32 ; af double-buffered; tail-prefetch wf4 first half ----------
  bf16x8 wf4a[4][4], wf4b[4][4];
  f32x4  bv4[4];
  {
    bf16x8 afA[8], afB[8];
    read_af8(afA, A32, 0);
    read_af8(afB, A32, 1);
    {
      f32x4 acc[4];
      mfma_pt(acc, wf3a, wf3b, afA, bv3);
      read_af8(afA, A32, 2);
      epi_pt4(acc, B32, 0);
    }
    {
      f32x4 acc[4];
      mfma_pt(acc, wf3a, wf3b, afB, bv3);
      read_af8(afB, A32, 3);
      epi_pt4(acc, B32, 1);
    }
    {
      f32x4 acc[4];
      mfma_pt(acc, wf3a, wf3b, afA, bv3);
      epi_pt4(acc, B32, 2);
    }
    {
      f32x4 acc[4];
      mfma_pt(acc, wf3a, wf3b, afB, bv3);
      load_wf_half(wf4a, wb + OFF_W4, 0);   // wf3 dead after this pt's MFMAs
      load_bv4(bv4, bws + 704);
      epi_pt4(acc, B32, 3);
    }
  }
  lds_barrier();

  // ---------- L4: B32 -> A32 ; head-load wf4 second half; tail-prefetch wf5 ----------
  bf16x8 wf5[8];
  f32x4  bv5;
  {
    load_wf_half(wf4b, wb + OFF_W4, 1);
    bf16x8 afA[8], afB[8];
    read_af8(afA, B32, 0);
    read_af8(afB, B32, 1);
    {
      f32x4 acc[4];
      mfma_pt(acc, wf4a, wf4b, afA, bv4);
      read_af8(afA, B32, 2);
      epi_pt4(acc, A32, 0);
    }
    {
      f32x4 acc[4];
      mfma_pt(acc, wf4a, wf4b, afB, bv4);
      read_af8(afB, B32, 3);
      epi_pt4(acc, A32, 1);
    }
    {
      f32x4 acc[4];
      mfma_pt(acc, wf4a, wf4b, afA, bv4);
      epi_pt4(acc, A32, 2);
    }
    {
      f32x4 acc[4];
      mfma_pt(acc, wf4a, wf4b, afB, bv4);
#pragma unroll
      for (int ks = 0; ks < 8; ++ks)        // wf5: 32 regs
        wf5[ks] = *reinterpret_cast<const bf16x8*>(
            wb + OFF_W5 + (wave * 16 + l15) * 256 + ks * 32 + quad * 8);
      bv5 = *reinterpret_cast<const f32x4*>(bws + 960 + wave * 16 + quad * 4);
      epi_pt4(acc, A32, 3);
    }
  }
  lds_barrier();

  // ---------- L5: A32 -> global ----------
  {
    float* out_base = out + (size_t)(c * 2 + bq) * 64 * kHW + hw0;
    bf16x8 afA[8], afB[8];
    read_af8(afA, A32, 0);
    read_af8(afB, A32, 1);
#pragma unroll
    for (int pt = 0; pt < 4; ++pt) {
      bf16x8 (&af)[8] = (pt & 1) ? afB : afA;
      f32x4 acc = bv5;
#pragma unroll
      for (int ks = 0; ks < 8; ++ks) acc = mf(wf5[ks], af[ks], acc);
      if (pt == 0) read_af8(afA, A32, 2);
      if (pt == 1) read_af8(afB, A32, 3);
      const int p = pt * 16 + l15;
      const int o = wave * 16 + quad * 4;
      float* dst = out_base + (size_t)o * kHW + p;
#pragma unroll
      for (int r = 0; r < 4; ++r) dst[(size_t)r * kHW] = acc[r];
    }
  }
}

extern "C" void kernel_launch(void* const* d_in, const int* in_sizes, int n_in,
                              void* d_out, int out_size, void* d_ws, size_t ws_size,
                              hipStream_t stream) {
  const float* feat  = (const float*)d_in[0];
  const float* times = (const float*)d_in[1];
  const float* w0 = (const float*)d_in[2];
  const float* b0 = (const float*)d_in[3];
  const float* w1 = (const float*)d_in[4];
  const float* b1 = (const float*)d_in[5];
  const float* w2 = (const float*)d_in[6];
  const float* b2 = (const float*)d_in[7];
  const float* w3 = (const float*)d_in[8];
  const float* b3 = (const float*)d_in[9];
  const float* w4 = (const float*)d_in[10];
  const float* b4 = (const float*)d_in[11];
  const float* w5 = (const float*)d_in[12];
  const float* b5 = (const float*)d_in[13];
  u16*   wb  = (u16*)d_ws;
  float* bws = (float*)((char*)d_ws + (size_t)W_TOTAL * 2);
  float* out = (float*)d_out;

  convert_weights<<<(W_TOTAL + B_TOTAL) / 256, 256, 0, stream>>>(
      w0, w1, w2, w3, w4, w5, b0, b1, b2, b3, b4, b5, wb, bws);

  if (ws_size >= WS_NEED) {
    u16* featT = (u16*)((char*)d_ws + FEAT_BYTE_OFF);
    convert_feat<<<1920, 256, 0, stream>>>(feat, featT);
    siren_main<true><<<5760, 256, 0, stream>>>(feat, times, wb, bws, featT, out);
  } else {
    siren_main<false><<<5760, 256, 0, stream>>>(feat, times, wb, bws, wb, out);
  }
}